// Round 1
// baseline (280.015 us; speedup 1.0000x reference)
//
#include <hip/hip_runtime.h>

// Problem constants (B,T,D,H fixed by the reference)
#define B_ 4
#define T_ 2048
#define D_ 1024
#define H_ 16

typedef unsigned short u16;
typedef __attribute__((ext_vector_type(8))) __bf16 bf16x8;
typedef __attribute__((ext_vector_type(8))) u16 u16x8;
typedef __attribute__((ext_vector_type(4))) float f32x4;

__device__ __forceinline__ u16 f2bf(float f) {      // f32 -> bf16 RNE
  unsigned u = __builtin_bit_cast(unsigned, f);
  u += 0x7FFFu + ((u >> 16) & 1u);
  return (u16)(u >> 16);
}

// async global->LDS, 16B per lane. LDS dest = wave-uniform base + lane*16.
__device__ __forceinline__ void gload16(const void* g, void* l) {
  __builtin_amdgcn_global_load_lds(
      (const __attribute__((address_space(1))) void*)g,
      (__attribute__((address_space(3))) void*)l, 16, 0, 0);
}

// ---------------- f32 -> bf16 convert (vectorized x4) ----------------
__global__ void cvt_bf16(const float* __restrict__ in, u16* __restrict__ out, int n4) {
  int i = blockIdx.x * 256 + threadIdx.x;
  if (i >= n4) return;
  const float4 v = ((const float4*)in)[i];
  ushort4 o;
  o.x = f2bf(v.x); o.y = f2bf(v.y); o.z = f2bf(v.z); o.w = f2bf(v.w);
  ((ushort4*)out)[i] = o;
}

// ---------------- GEMM: C[M,N] = alpha * A[M,K] @ Bw[N,K]^T (+bias)(*rowmask) ----
// 128x128 tile, BK=64, 256 threads = 4 waves (2x2), 16x16x32 bf16 MFMA.
// LDS XOR-swizzle (byte ^= (row&7)<<4) applied via pre-swizzled global source
// (global_load_lds writes linearly), un-swizzled on the ds_read side.
template<bool OUT_BF16, bool BIAS, bool MASK>
__global__ __launch_bounds__(256, 2) void gemm_bt(
    const u16* __restrict__ A, const u16* __restrict__ Bw,
    void* __restrict__ C, const float* __restrict__ bias,
    const unsigned char* __restrict__ rowmask,
    int M, int N, int Kd, float alpha)
{
  __shared__ __align__(16) u16 sA[128 * 64];
  __shared__ __align__(16) u16 sB[128 * 64];
  const int tid = threadIdx.x;
  const int lane = tid & 63, wave = tid >> 6;
  const int g = lane >> 4, s15 = lane & 15;
  const int bm = blockIdx.x * 128, bn = blockIdx.y * 128;
  const int wr = wave >> 1, wc = wave & 1;

  // staging geometry: chunk = 8 rows x 128B; lane covers row lane>>3, 16B col (lane&7)*16
  const int srow = lane >> 3;
  const int scol = ((lane & 7) ^ srow) << 3;   // swizzled source col (elements)

  f32x4 acc[4][4] = {};

  const int KT = Kd >> 6;
  for (int kt = 0; kt < KT; ++kt) {
    __syncthreads();
    const int k0 = kt << 6;
#pragma unroll
    for (int c = 0; c < 4; ++c) {
      const int chunk = c * 4 + wave;
      gload16(A + (size_t)(bm + chunk * 8 + srow) * Kd + k0 + scol, (char*)sA + chunk * 1024);
      gload16(Bw + (size_t)(bn + chunk * 8 + srow) * Kd + k0 + scol, (char*)sB + chunk * 1024);
    }
    __syncthreads();
#pragma unroll
    for (int kk = 0; kk < 2; ++kk) {
      const int cb = ((kk << 6) | (g << 4)) ^ ((s15 & 7) << 4);
      bf16x8 af[4], bf[4];
#pragma unroll
      for (int mm = 0; mm < 4; ++mm)
        af[mm] = *(const bf16x8*)((const char*)sA + (wr * 64 + mm * 16 + s15) * 128 + cb);
#pragma unroll
      for (int nn = 0; nn < 4; ++nn)
        bf[nn] = *(const bf16x8*)((const char*)sB + (wc * 64 + nn * 16 + s15) * 128 + cb);
#pragma unroll
      for (int mm = 0; mm < 4; ++mm)
#pragma unroll
        for (int nn = 0; nn < 4; ++nn)
          acc[mm][nn] = __builtin_amdgcn_mfma_f32_16x16x32_bf16(af[mm], bf[nn], acc[mm][nn], 0, 0, 0);
    }
  }

  // epilogue: C/D layout col=lane&15, row=(lane>>4)*4+reg
#pragma unroll
  for (int mm = 0; mm < 4; ++mm) {
#pragma unroll
    for (int nn = 0; nn < 4; ++nn) {
      const int col = bn + wc * 64 + nn * 16 + s15;
      const int row0 = bm + wr * 64 + mm * 16 + (g << 2);
      const float bv = BIAS ? bias[col] : 0.f;
#pragma unroll
      for (int r = 0; r < 4; ++r) {
        float v = acc[mm][nn][r] * alpha + bv;
        if (MASK) v = rowmask[row0 + r] ? 0.f : v;
        if (OUT_BF16) ((u16*)C)[(size_t)(row0 + r) * N + col] = f2bf(v);
        else          ((float*)C)[(size_t)(row0 + r) * N + col] = v;
      }
    }
  }
}

// ---------------- Flash attention (causal + key padding mask) ----------------
// Grid: (T/128, B*H). 256 threads = 4 waves; wave owns 32 q-rows.
// Swapped QK^T: S^T = mfma(K_frag, Q_frag) -> softmax row i == lane&15 (2 shfl_xor reduce).
__global__ __launch_bounds__(256, 2) void attn_fwd(
    const u16* __restrict__ Q, const u16* __restrict__ K,
    const u16* __restrict__ V, const unsigned char* __restrict__ pm,
    u16* __restrict__ O)
{
  __shared__ __align__(16) u16 sK[64 * 64];        // [j][d] swizzled, row=128B
  __shared__ __align__(16) u16 sVt[64 * 72];       // [d][j], stride 144B (pad 8)
  __shared__ __align__(16) u16 sP[4][32 * 72];     // per-wave P [i][j]

  const int tid = threadIdx.x;
  const int lane = tid & 63, wave = tid >> 6;
  const int g = lane >> 4, s15 = lane & 15;
  const int b = blockIdx.y >> 4, h = blockIdx.y & 15;
  const int q0 = blockIdx.x * 128;
  const int qw = q0 + wave * 32;
  const unsigned char* pmb = pm + b * T_;
  const size_t tokbase = (size_t)b * T_;

  // Q fragments (B-operand): col=lane&15 = q-row-in-frag, k = d
  bf16x8 qf[2][2];
#pragma unroll
  for (int nf = 0; nf < 2; ++nf)
#pragma unroll
    for (int ks = 0; ks < 2; ++ks)
      qf[nf][ks] = *(const bf16x8*)(Q + (tokbase + qw + nf * 16 + s15) * D_ + h * 64 + ks * 32 + g * 8);

  f32x4 o[2][4] = {};
  float mrow[2] = {-1e30f, -1e30f};
  float lrow[2] = {0.f, 0.f};

  const int kj = tid >> 2, kc = tid & 3;   // K staging: row, 16-elem chunk
  const int vj = tid & 63, vd = tid >> 6;  // V staging: row, 16-elem d-block
  const int ntiles = (q0 + 128) >> 6;

  for (int t = 0; t < ntiles; ++t) {
    const int kv0 = t << 6;
    __syncthreads();
    { // stage K, swizzled
      const u16* kg = K + (tokbase + kv0 + kj) * D_ + h * 64 + kc * 16;
      u16x8 k0 = *(const u16x8*)kg;
      u16x8 k1 = *(const u16x8*)(kg + 8);
      const int swz = (kj & 7) << 4;
      char* kbp = (char*)sK + kj * 128;
      *(u16x8*)(kbp + ((kc * 32) ^ swz)) = k0;
      *(u16x8*)(kbp + ((kc * 32 + 16) ^ swz)) = k1;
    }
    { // stage V transposed: sVt[d][j]
      const u16* vg = V + (tokbase + kv0 + vj) * D_ + h * 64 + vd * 16;
      u16x8 v0 = *(const u16x8*)vg;
      u16x8 v1 = *(const u16x8*)(vg + 8);
#pragma unroll
      for (int e = 0; e < 8; ++e) sVt[(vd * 16 + e) * 72 + vj] = v0[e];
#pragma unroll
      for (int e = 0; e < 8; ++e) sVt[(vd * 16 + 8 + e) * 72 + vj] = v1[e];
    }
    __syncthreads();

    // S^T[j,i] = sum_d K[j,d] Q[i,d]   (Q pre-scaled by 1/sqrt(64) in projection)
    f32x4 st[4][2] = {};
#pragma unroll
    for (int ks = 0; ks < 2; ++ks) {
      const int cb = ((ks << 6) | (g << 4)) ^ ((s15 & 7) << 4);
      bf16x8 kf[4];
#pragma unroll
      for (int jf = 0; jf < 4; ++jf)
        kf[jf] = *(const bf16x8*)((const char*)sK + (jf * 16 + s15) * 128 + cb);
#pragma unroll
      for (int jf = 0; jf < 4; ++jf)
#pragma unroll
        for (int nf = 0; nf < 2; ++nf)
          st[jf][nf] = __builtin_amdgcn_mfma_f32_16x16x32_bf16(kf[jf], qf[nf][ks], st[jf][nf], 0, 0, 0);
    }

    // causal + key-padding mask. element: j = kv0+jf*16+g*4+r, i = qw+nf*16+s15
#pragma unroll
    for (int jf = 0; jf < 4; ++jf) {
      const int jb = kv0 + jf * 16 + g * 4;
      uchar4 pmv = *(const uchar4*)(pmb + jb);
      const unsigned char* pmr = (const unsigned char*)&pmv;
#pragma unroll
      for (int nf = 0; nf < 2; ++nf) {
        const int ig = qw + nf * 16 + s15;
#pragma unroll
        for (int r = 0; r < 4; ++r)
          if (jb + r > ig || pmr[r]) st[jf][nf][r] = -1e30f;
      }
    }

    // online softmax (row = i = lane&15): reduce across lane-groups via shfl_xor
    float acorr[2];
#pragma unroll
    for (int nf = 0; nf < 2; ++nf) {
      float tm = -1e30f;
#pragma unroll
      for (int jf = 0; jf < 4; ++jf)
#pragma unroll
        for (int r = 0; r < 4; ++r) tm = fmaxf(tm, st[jf][nf][r]);
      tm = fmaxf(tm, __shfl_xor(tm, 16));
      tm = fmaxf(tm, __shfl_xor(tm, 32));
      const float mnew = fmaxf(mrow[nf], tm);
      acorr[nf] = __expf(mrow[nf] - mnew);
      mrow[nf] = mnew;
      float sum = 0.f;
#pragma unroll
      for (int jf = 0; jf < 4; ++jf)
#pragma unroll
        for (int r = 0; r < 4; ++r) {
          const float p = __expf(st[jf][nf][r] - mnew);
          st[jf][nf][r] = p;
          sum += p;
        }
      sum += __shfl_xor(sum, 16);
      sum += __shfl_xor(sum, 32);
      lrow[nf] = lrow[nf] * acorr[nf] + sum;
    }

    // write P (bf16) to per-wave LDS [i][j]
    u16* pw = sP[wave];
#pragma unroll
    for (int jf = 0; jf < 4; ++jf)
#pragma unroll
      for (int nf = 0; nf < 2; ++nf) {
        ushort4 pk;
        pk.x = f2bf(st[jf][nf][0]); pk.y = f2bf(st[jf][nf][1]);
        pk.z = f2bf(st[jf][nf][2]); pk.w = f2bf(st[jf][nf][3]);
        *(ushort4*)(pw + (nf * 16 + s15) * 72 + jf * 16 + g * 4) = pk;
      }
    __syncthreads();   // cross-lane LDS RAW: P written by other lanes of the wave

    // rescale O by exp(m_old - m_new); O rows live at g*4+r -> fetch stat via shfl
#pragma unroll
    for (int mf = 0; mf < 2; ++mf)
#pragma unroll
      for (int r = 0; r < 4; ++r) {
        const float ac = __shfl(acorr[mf], g * 4 + r);
#pragma unroll
        for (int nd = 0; nd < 4; ++nd) o[mf][nd][r] *= ac;
      }

    // O += P @ V : A = P (from sP), B = V (from sVt, contiguous in j)
#pragma unroll
    for (int kb = 0; kb < 2; ++kb) {
      bf16x8 pf[2], vf[4];
#pragma unroll
      for (int mf = 0; mf < 2; ++mf)
        pf[mf] = *(const bf16x8*)(pw + (mf * 16 + s15) * 72 + kb * 32 + g * 8);
#pragma unroll
      for (int nd = 0; nd < 4; ++nd)
        vf[nd] = *(const bf16x8*)(sVt + (nd * 16 + s15) * 72 + kb * 32 + g * 8);
#pragma unroll
      for (int mf = 0; mf < 2; ++mf)
#pragma unroll
        for (int nd = 0; nd < 4; ++nd)
          o[mf][nd] = __builtin_amdgcn_mfma_f32_16x16x32_bf16(pf[mf], vf[nd], o[mf][nd], 0, 0, 0);
    }
  }

  // finalize: O / l, store bf16 [B*T, D] (head h at cols h*64..)
#pragma unroll
  for (int mf = 0; mf < 2; ++mf)
#pragma unroll
    for (int r = 0; r < 4; ++r) {
      const float lr = __shfl(lrow[mf], g * 4 + r);
      const float inv = 1.f / lr;
      u16* orow = O + (tokbase + qw + mf * 16 + g * 4 + r) * D_ + h * 64;
#pragma unroll
      for (int nd = 0; nd < 4; ++nd)
        orow[nd * 16 + s15] = f2bf(o[mf][nd][r] * inv);
    }
}

// ---------------- launcher ----------------
extern "C" void kernel_launch(void* const* d_in, const int* in_sizes, int n_in,
                              void* d_out, int out_size, void* d_ws, size_t ws_size,
                              hipStream_t stream)
{
  const float* x  = (const float*)d_in[0];
  const unsigned char* pm = (const unsigned char*)d_in[1];
  const float* Wq = (const float*)d_in[2];
  const float* Wk = (const float*)d_in[3];
  const float* Wv = (const float*)d_in[4];
  const float* Wo = (const float*)d_in[5];
  const float* bo = (const float*)d_in[6];
  float* out = (float*)d_out;

  // workspace carve (~88 MB)
  char* w = (char*)d_ws;
  u16* xb  = (u16*)w; w += (size_t)B_ * T_ * D_ * 2;
  u16* wqb = (u16*)w; w += (size_t)D_ * D_ * 2;
  u16* wkb = (u16*)w; w += (size_t)D_ * D_ * 2;
  u16* wvb = (u16*)w; w += (size_t)D_ * D_ * 2;
  u16* wob = (u16*)w; w += (size_t)D_ * D_ * 2;
  u16* qb  = (u16*)w; w += (size_t)B_ * T_ * D_ * 2;
  u16* kb  = (u16*)w; w += (size_t)B_ * T_ * D_ * 2;
  u16* vb  = (u16*)w; w += (size_t)B_ * T_ * D_ * 2;
  u16* ao  = (u16*)w; w += (size_t)B_ * T_ * D_ * 2;

  const int nx4 = B_ * T_ * D_ / 4;   // 2097152
  const int nw4 = D_ * D_ / 4;        // 262144
  cvt_bf16<<<nx4 / 256, 256, 0, stream>>>(x, xb, nx4);
  cvt_bf16<<<nw4 / 256, 256, 0, stream>>>(Wq, wqb, nw4);
  cvt_bf16<<<nw4 / 256, 256, 0, stream>>>(Wk, wkb, nw4);
  cvt_bf16<<<nw4 / 256, 256, 0, stream>>>(Wv, wvb, nw4);
  cvt_bf16<<<nw4 / 256, 256, 0, stream>>>(Wo, wob, nw4);

  dim3 gg(B_ * T_ / 128, D_ / 128);   // (64, 8)
  // scale 1/sqrt(HD)=0.125 folded (exactly) into Q projection
  gemm_bt<true, false, false><<<gg, 256, 0, stream>>>(xb, wqb, qb, nullptr, nullptr, B_ * T_, D_, D_, 0.125f);
  gemm_bt<true, false, false><<<gg, 256, 0, stream>>>(xb, wkb, kb, nullptr, nullptr, B_ * T_, D_, D_, 1.0f);
  gemm_bt<true, false, false><<<gg, 256, 0, stream>>>(xb, wvb, vb, nullptr, nullptr, B_ * T_, D_, D_, 1.0f);

  attn_fwd<<<dim3(T_ / 128, B_ * H_), 256, 0, stream>>>(qb, kb, vb, pm, ao);

  gemm_bt<false, true, true><<<gg, 256, 0, stream>>>(ao, wob, out, bo, pm, B_ * T_, D_, D_, 1.0f);
}

// Round 2
// 170.302 us; speedup vs baseline: 1.6442x; 1.6442x over previous
//
#include <hip/hip_runtime.h>

#define B_ 4
#define T_ 2048
#define D_ 1024
#define H_ 16
#define BT_ (B_ * T_)
#define QSCALE (0.125f * 1.44269504088896f)   // 1/sqrt(64) * log2(e), exp2-domain softmax

typedef unsigned short u16;
typedef __attribute__((ext_vector_type(8))) __bf16 bf16x8;
typedef __attribute__((ext_vector_type(4))) float f32x4;

__device__ __forceinline__ u16 f2bf(float f) {      // f32 -> bf16 RNE
  unsigned u = __builtin_bit_cast(unsigned, f);
  u += 0x7FFFu + ((u >> 16) & 1u);
  return (u16)(u >> 16);
}

__device__ __forceinline__ void gload16(const void* g, void* l) {
  __builtin_amdgcn_global_load_lds(
      (const __attribute__((address_space(1))) void*)g,
      (__attribute__((address_space(3))) void*)l, 16, 0, 0);
}

// ---------------- f32 -> bf16 convert ----------------
__global__ void cvt_bf16(const float* __restrict__ in, u16* __restrict__ out, int n4) {
  int i = blockIdx.x * 256 + threadIdx.x;
  if (i >= n4) return;
  const float4 v = ((const float4*)in)[i];
  ushort4 o;
  o.x = f2bf(v.x); o.y = f2bf(v.y); o.z = f2bf(v.z); o.w = f2bf(v.w);
  ((ushort4*)out)[i] = o;
}

// ---------------- per-64-token padding flags ----------------
__global__ void pm_flags(const unsigned char* __restrict__ pm, unsigned char* __restrict__ fl) {
  int i = threadIdx.x;                       // 0..127 = b*32 + tile
  const unsigned long long* p = (const unsigned long long*)(pm + i * 64);
  unsigned long long acc = 0;
#pragma unroll
  for (int k = 0; k < 8; ++k) acc |= p[k];
  fl[i] = acc ? 1 : 0;
}

// ---------------- GEMM: 128x128 tile, BK=64, 4 waves, swizzled LDS ----------------
// MODE 1: fused QKV  (A[8192,1024] @ Wqkv[3072,1024]^T) -> Cq (x QSCALE), Ck, Cvt (transposed)
// MODE 0: out-proj   -> Cf f32 + bias, rowmask zeroing
template<int MODE>
__global__ __launch_bounds__(256, 2) void gemm_bt(
    const u16* __restrict__ A, const u16* __restrict__ Bw,
    float* __restrict__ Cf, const float* __restrict__ bias,
    const unsigned char* __restrict__ rowmask,
    u16* __restrict__ Cq, u16* __restrict__ Ck, u16* __restrict__ Cvt)
{
  __shared__ __align__(16) u16 sA[128 * 64];
  __shared__ __align__(16) u16 sB[128 * 64];
  const int tid = threadIdx.x;
  const int lane = tid & 63, wave = tid >> 6;
  const int g = lane >> 4, s15 = lane & 15;
  const int bm = blockIdx.x * 128, bn = blockIdx.y * 128;
  const int wr = wave >> 1, wc = wave & 1;

  const int srow = lane >> 3;
  const int scol = ((lane & 7) ^ srow) << 3;

  f32x4 acc[4][4] = {};

  for (int kt = 0; kt < 16; ++kt) {
    __syncthreads();
    const int k0 = kt << 6;
#pragma unroll
    for (int c = 0; c < 4; ++c) {
      const int chunk = c * 4 + wave;
      gload16(A  + (size_t)(bm + chunk * 8 + srow) * 1024 + k0 + scol, (char*)sA + chunk * 1024);
      gload16(Bw + (size_t)(bn + chunk * 8 + srow) * 1024 + k0 + scol, (char*)sB + chunk * 1024);
    }
    __syncthreads();
#pragma unroll
    for (int kk = 0; kk < 2; ++kk) {
      const int cb = ((kk << 6) | (g << 4)) ^ ((s15 & 7) << 4);
      bf16x8 af[4], bf[4];
#pragma unroll
      for (int mm = 0; mm < 4; ++mm)
        af[mm] = *(const bf16x8*)((const char*)sA + (wr * 64 + mm * 16 + s15) * 128 + cb);
#pragma unroll
      for (int nn = 0; nn < 4; ++nn)
        bf[nn] = *(const bf16x8*)((const char*)sB + (wc * 64 + nn * 16 + s15) * 128 + cb);
#pragma unroll
      for (int mm = 0; mm < 4; ++mm)
#pragma unroll
        for (int nn = 0; nn < 4; ++nn)
          acc[mm][nn] = __builtin_amdgcn_mfma_f32_16x16x32_bf16(af[mm], bf[nn], acc[mm][nn], 0, 0, 0);
    }
  }

  if (MODE == 1) {
    const int region = bn >> 10;               // 0=Q 1=K 2=V (block-uniform)
    const float a = (region == 0) ? QSCALE : 1.f;
#pragma unroll
    for (int mm = 0; mm < 4; ++mm)
#pragma unroll
      for (int nn = 0; nn < 4; ++nn) {
        const int col = bn + wc * 64 + nn * 16 + s15;
        const int colr = col & 1023;
        const int row0 = bm + wr * 64 + mm * 16 + (g << 2);
        if (region == 2) {
          ushort4 w;
          w.x = f2bf(acc[mm][nn][0]); w.y = f2bf(acc[mm][nn][1]);
          w.z = f2bf(acc[mm][nn][2]); w.w = f2bf(acc[mm][nn][3]);
          *(ushort4*)(Cvt + (size_t)colr * BT_ + row0) = w;   // V^T[d][token]
        } else {
          u16* dst = region ? Ck : Cq;
#pragma unroll
          for (int r = 0; r < 4; ++r)
            dst[(size_t)(row0 + r) * 1024 + colr] = f2bf(acc[mm][nn][r] * a);
        }
      }
  } else {
#pragma unroll
    for (int mm = 0; mm < 4; ++mm)
#pragma unroll
      for (int nn = 0; nn < 4; ++nn) {
        const int col = bn + wc * 64 + nn * 16 + s15;
        const int row0 = bm + wr * 64 + mm * 16 + (g << 2);
        const float bv = bias[col];
#pragma unroll
        for (int r = 0; r < 4; ++r) {
          float v = acc[mm][nn][r] + bv;
          v = rowmask[row0 + r] ? 0.f : v;
          Cf[(size_t)(row0 + r) * 1024 + col] = v;
        }
      }
  }
}

// ---------------- Flash attention (causal), O^T = V^T @ P^T, P in registers ----------
// Grid: (B*H, T/128). 4 waves x 32 q-rows. KV tile 64, double-buffered LDS,
// global_load_lds staging (swizzled source), one barrier per tile.
__global__ __launch_bounds__(256, 2) void attn_fwd(
    const u16* __restrict__ Q, const u16* __restrict__ K,
    const u16* __restrict__ VT, const unsigned char* __restrict__ pm,
    const unsigned char* __restrict__ tileflag, u16* __restrict__ O)
{
  __shared__ __align__(16) u16 sK[2][64 * 64];
  __shared__ __align__(16) u16 sV[2][64 * 64];
  const int tid = threadIdx.x;
  const int lane = tid & 63, wave = tid >> 6;
  const int g = lane >> 4, s15 = lane & 15;
  const int bh = blockIdx.x, b = bh >> 4, h = bh & 15;
  const int q0 = blockIdx.y * 128;
  const int qw = q0 + wave * 32;
  const size_t tokbase = (size_t)b * T_;

  // Q fragments (B-operand of QK^T): lane holds Q[qw+nf*16+s15][ks*32+g*8 ..+7]
  bf16x8 qf[2][2];
#pragma unroll
  for (int nf = 0; nf < 2; ++nf)
#pragma unroll
    for (int ks = 0; ks < 2; ++ks)
      qf[nf][ks] = *(const bf16x8*)(Q + (tokbase + qw + nf * 16 + s15) * D_ + h * 64 + ks * 32 + g * 8);

  // staging geometry: per wave-call, 8 rows x 128B; source chunk pre-swizzled
  const int srow = lane >> 3;
  const int sc = (lane & 7) ^ srow;
  const u16* Kb0 = K + tokbase * D_ + h * 64 + sc * 8;
  const u16* Vb0 = VT + (size_t)(h * 64) * BT_ + tokbase + sc * 8;

  f32x4 o[2][4] = {};
  float m_[2] = {-1e30f, -1e30f}, l_[2] = {0.f, 0.f};

  const int nt = (q0 >> 6) + 2;

  // prologue stage tile 0
#pragma unroll
  for (int c = 0; c < 2; ++c) {
    const int r8 = (c * 4 + wave) * 8;
    gload16(Kb0 + (size_t)(r8 + srow) * D_,  (char*)(&sK[0][0]) + (c * 4 + wave) * 1024);
    gload16(Vb0 + (size_t)(r8 + srow) * BT_, (char*)(&sV[0][0]) + (c * 4 + wave) * 1024);
  }
  __syncthreads();

  for (int t = 0; t < nt; ++t) {
    const int kv0 = t << 6;
    if (t + 1 < nt) {         // stage next tile into other buffer (overlaps compute)
      const int nb = (t + 1) & 1;
#pragma unroll
      for (int c = 0; c < 2; ++c) {
        const int r8 = (c * 4 + wave) * 8;
        gload16(Kb0 + (size_t)(kv0 + 64 + r8 + srow) * D_,  (char*)(&sK[nb][0]) + (c * 4 + wave) * 1024);
        gload16(Vb0 + (size_t)(r8 + srow) * BT_ + kv0 + 64, (char*)(&sV[nb][0]) + (c * 4 + wave) * 1024);
      }
    }

    if (kv0 <= qw + 31) {     // wave-uniform: this wave still has causal work here
      const u16* kb_ = &sK[t & 1][0];
      const u16* vb_ = &sV[t & 1][0];

      // S^T[j][i] = sum_d K[j,d] * Q[i,d]   (log2e pre-folded into Q)
      f32x4 st[4][2] = {};
#pragma unroll
      for (int ks = 0; ks < 2; ++ks) {
        bf16x8 kf[4];
#pragma unroll
        for (int jf = 0; jf < 4; ++jf)
          kf[jf] = *(const bf16x8*)(kb_ + (jf * 16 + s15) * 64 + (((ks * 4 + g) ^ (s15 & 7)) << 3));
#pragma unroll
        for (int jf = 0; jf < 4; ++jf)
#pragma unroll
          for (int nf = 0; nf < 2; ++nf)
            st[jf][nf] = __builtin_amdgcn_mfma_f32_16x16x32_bf16(kf[jf], qf[nf][ks], st[jf][nf], 0, 0, 0);
      }

      // causal mask (only diagonal-crossing tiles); j = kv0+jf*16+g*4+r, i = qw+nf*16+s15
#pragma unroll
      for (int nf = 0; nf < 2; ++nf) {
        if (kv0 + 63 > qw + nf * 16) {
          const int iq = qw + nf * 16 + s15;
#pragma unroll
          for (int jf = 0; jf < 4; ++jf) {
            const int jb = kv0 + jf * 16 + g * 4;
#pragma unroll
            for (int r = 0; r < 4; ++r)
              if (jb + r > iq) st[jf][nf][r] = -1e30f;
          }
        }
      }
      if (tileflag[b * 32 + t]) {   // key padding (uniform branch; all-false fast path)
#pragma unroll
        for (int jf = 0; jf < 4; ++jf) {
          const int jb = kv0 + jf * 16 + g * 4;
          uchar4 p4 = *(const uchar4*)(pm + b * T_ + jb);
          const unsigned char* pr = (const unsigned char*)&p4;
#pragma unroll
          for (int r = 0; r < 4; ++r)
            if (pr[r]) { st[jf][0][r] = -1e30f; st[jf][1][r] = -1e30f; }
        }
      }

      // online softmax; row i = s15 -> stats lane-local, reduce over g via shfl_xor
      float acorr[2];
#pragma unroll
      for (int nf = 0; nf < 2; ++nf) {
        float tm = -1e30f;
#pragma unroll
        for (int jf = 0; jf < 4; ++jf)
#pragma unroll
          for (int r = 0; r < 4; ++r) tm = fmaxf(tm, st[jf][nf][r]);
        tm = fmaxf(tm, __shfl_xor(tm, 16));
        tm = fmaxf(tm, __shfl_xor(tm, 32));
        const float mn = fmaxf(m_[nf], tm);
        acorr[nf] = __builtin_amdgcn_exp2f(m_[nf] - mn);
        m_[nf] = mn;
        float s = 0.f;
#pragma unroll
        for (int jf = 0; jf < 4; ++jf)
#pragma unroll
          for (int r = 0; r < 4; ++r) {
            const float p = __builtin_amdgcn_exp2f(st[jf][nf][r] - mn);
            st[jf][nf][r] = p;
            s += p;
          }
        s += __shfl_xor(s, 16);
        s += __shfl_xor(s, 32);
        l_[nf] = l_[nf] * acorr[nf] + s;
#pragma unroll
        for (int df = 0; df < 4; ++df) o[nf][df] *= acorr[nf];   // lane-local rescale
      }

      // O^T += V^T @ P^T. P fragments built in-register via cvt_pk + permlane swaps.
#pragma unroll
      for (int kb2 = 0; kb2 < 2; ++kb2) {
        bf16x8 vf[4];
#pragma unroll
        for (int df = 0; df < 4; ++df)
          vf[df] = *(const bf16x8*)(vb_ + (df * 16 + s15) * 64 + (((kb2 * 4 + g) ^ (s15 & 7)) << 3));
#pragma unroll
        for (int nf = 0; nf < 2; ++nf) {
          unsigned w00, w01, w10, w11;
          asm("v_cvt_pk_bf16_f32 %0, %1, %2" : "=v"(w00) : "v"(st[2*kb2][nf][0]),   "v"(st[2*kb2][nf][1]));
          asm("v_cvt_pk_bf16_f32 %0, %1, %2" : "=v"(w01) : "v"(st[2*kb2][nf][2]),   "v"(st[2*kb2][nf][3]));
          asm("v_cvt_pk_bf16_f32 %0, %1, %2" : "=v"(w10) : "v"(st[2*kb2+1][nf][0]), "v"(st[2*kb2+1][nf][1]));
          asm("v_cvt_pk_bf16_f32 %0, %1, %2" : "=v"(w11) : "v"(st[2*kb2+1][nf][2]), "v"(st[2*kb2+1][nf][3]));
          // (X,Y) -> p32: X'=[Xg0,Xg1,Yg0,Yg1], Y'=[Xg2,Xg3,Yg2,Yg3]; p16: X''=[Xg0,Xg2,Yg0,Yg2]=W0, Y''=W2
          asm("v_permlane32_swap_b32 %0, %1" : "+v"(w00), "+v"(w10));
          asm("v_permlane16_swap_b32 %0, %1" : "+v"(w00), "+v"(w10));
          asm("v_permlane32_swap_b32 %0, %1" : "+v"(w01), "+v"(w11));
          asm("v_permlane16_swap_b32 %0, %1" : "+v"(w01), "+v"(w11));
          union { unsigned u[4]; bf16x8 v; } pf;
          pf.u[0] = w00; pf.u[1] = w01; pf.u[2] = w10; pf.u[3] = w11;
#pragma unroll
          for (int df = 0; df < 4; ++df)
            o[nf][df] = __builtin_amdgcn_mfma_f32_16x16x32_bf16(vf[df], pf.v, o[nf][df], 0, 0, 0);
        }
      }
    }
    __syncthreads();   // publishes stage(t+1); all reads of buf[t&1] done
  }

  // finalize (all lane-local): O[i][d] = O^T[d][i] / l
#pragma unroll
  for (int nf = 0; nf < 2; ++nf) {
    const float inv = 1.f / l_[nf];
    u16* orow = O + (tokbase + qw + nf * 16 + s15) * D_ + h * 64 + g * 4;
#pragma unroll
    for (int df = 0; df < 4; ++df) {
      ushort4 w;
      w.x = f2bf(o[nf][df][0] * inv); w.y = f2bf(o[nf][df][1] * inv);
      w.z = f2bf(o[nf][df][2] * inv); w.w = f2bf(o[nf][df][3] * inv);
      *(ushort4*)(orow + df * 16) = w;
    }
  }
}

// ---------------- launcher ----------------
extern "C" void kernel_launch(void* const* d_in, const int* in_sizes, int n_in,
                              void* d_out, int out_size, void* d_ws, size_t ws_size,
                              hipStream_t stream)
{
  const float* x  = (const float*)d_in[0];
  const unsigned char* pm = (const unsigned char*)d_in[1];
  const float* Wq = (const float*)d_in[2];
  const float* Wk = (const float*)d_in[3];
  const float* Wv = (const float*)d_in[4];
  const float* Wo = (const float*)d_in[5];
  const float* bo = (const float*)d_in[6];
  float* out = (float*)d_out;

  char* w = (char*)d_ws;
  u16* xb  = (u16*)w; w += (size_t)BT_ * D_ * 2;
  u16* wqb = (u16*)w; w += (size_t)D_ * D_ * 2;   // wq|wk|wv contiguous -> fused [3072,1024]
  u16* wkb = (u16*)w; w += (size_t)D_ * D_ * 2;
  u16* wvb = (u16*)w; w += (size_t)D_ * D_ * 2;
  u16* wob = (u16*)w; w += (size_t)D_ * D_ * 2;
  u16* qb  = (u16*)w; w += (size_t)BT_ * D_ * 2;
  u16* kbf = (u16*)w; w += (size_t)BT_ * D_ * 2;
  u16* vt  = (u16*)w; w += (size_t)BT_ * D_ * 2;  // V^T [1024][8192]
  u16* ao  = (u16*)w; w += (size_t)BT_ * D_ * 2;
  unsigned char* flags = (unsigned char*)w; w += 256;

  const int nx4 = BT_ * D_ / 4;
  const int nw4 = D_ * D_ / 4;
  cvt_bf16<<<nx4 / 256, 256, 0, stream>>>(x, xb, nx4);
  cvt_bf16<<<nw4 / 256, 256, 0, stream>>>(Wq, wqb, nw4);
  cvt_bf16<<<nw4 / 256, 256, 0, stream>>>(Wk, wkb, nw4);
  cvt_bf16<<<nw4 / 256, 256, 0, stream>>>(Wv, wvb, nw4);
  cvt_bf16<<<nw4 / 256, 256, 0, stream>>>(Wo, wob, nw4);
  pm_flags<<<1, 128, 0, stream>>>(pm, flags);

  gemm_bt<1><<<dim3(64, 24), 256, 0, stream>>>(xb, wqb, nullptr, nullptr, nullptr, qb, kbf, vt);

  attn_fwd<<<dim3(B_ * H_, T_ / 128), 256, 0, stream>>>(qb, kbf, vt, pm, flags, ao);

  gemm_bt<0><<<dim3(64, 8), 256, 0, stream>>>(ao, wob, out, bo, pm, nullptr, nullptr, nullptr);
}

// Round 3
// 159.276 us; speedup vs baseline: 1.7581x; 1.0692x over previous
//
#include <hip/hip_runtime.h>

#define B_ 4
#define T_ 2048
#define D_ 1024
#define H_ 16
#define BT_ (B_ * T_)
#define QSCALE (0.125f * 1.44269504088896f)   // 1/sqrt(64) * log2(e), exp2-domain softmax

typedef unsigned short u16;
typedef __attribute__((ext_vector_type(8))) __bf16 bf16x8;
typedef __attribute__((ext_vector_type(4))) float f32x4;

__device__ __forceinline__ u16 f2bf(float f) {      // f32 -> bf16 RNE
  unsigned u = __builtin_bit_cast(unsigned, f);
  u += 0x7FFFu + ((u >> 16) & 1u);
  return (u16)(u >> 16);
}

__device__ __forceinline__ void gload16(const void* g, void* l) {
  __builtin_amdgcn_global_load_lds(
      (const __attribute__((address_space(1))) void*)g,
      (__attribute__((address_space(3))) void*)l, 16, 0, 0);
}

// ---------------- f32 -> bf16 convert ----------------
__global__ void cvt_bf16(const float* __restrict__ in, u16* __restrict__ out, int n4) {
  int i = blockIdx.x * 256 + threadIdx.x;
  if (i >= n4) return;
  const float4 v = ((const float4*)in)[i];
  ushort4 o;
  o.x = f2bf(v.x); o.y = f2bf(v.y); o.z = f2bf(v.z); o.w = f2bf(v.w);
  ((ushort4*)out)[i] = o;
}

// ---------------- per-64-token padding flags ----------------
__global__ void pm_flags(const unsigned char* __restrict__ pm, unsigned char* __restrict__ fl) {
  int i = threadIdx.x;                       // 0..127 = b*32 + tile
  const unsigned long long* p = (const unsigned long long*)(pm + i * 64);
  unsigned long long acc = 0;
#pragma unroll
  for (int k = 0; k < 8; ++k) acc |= p[k];
  fl[i] = acc ? 1 : 0;
}

// ---------------- GEMM: 128x128 tile, BK=64, 4 waves, swizzled LDS ----------------
// MODE 1: fused QKV  (A[8192,1024] @ Wqkv[3072,1024]^T) -> Cq (x QSCALE), Ck, Cvt (transposed)
// MODE 0: out-proj   -> Cf f32 + bias, rowmask zeroing
template<int MODE>
__global__ __launch_bounds__(256, 2) void gemm_bt(
    const u16* __restrict__ A, const u16* __restrict__ Bw,
    float* __restrict__ Cf, const float* __restrict__ bias,
    const unsigned char* __restrict__ rowmask,
    u16* __restrict__ Cq, u16* __restrict__ Ck, u16* __restrict__ Cvt)
{
  __shared__ __align__(16) u16 sA[128 * 64];
  __shared__ __align__(16) u16 sB[128 * 64];
  const int tid = threadIdx.x;
  const int lane = tid & 63, wave = tid >> 6;
  const int g = lane >> 4, s15 = lane & 15;
  const int bm = blockIdx.x * 128, bn = blockIdx.y * 128;
  const int wr = wave >> 1, wc = wave & 1;

  const int srow = lane >> 3;
  const int scol = ((lane & 7) ^ srow) << 3;

  f32x4 acc[4][4] = {};

  for (int kt = 0; kt < 16; ++kt) {
    __syncthreads();
    const int k0 = kt << 6;
#pragma unroll
    for (int c = 0; c < 4; ++c) {
      const int chunk = c * 4 + wave;
      gload16(A  + (size_t)(bm + chunk * 8 + srow) * 1024 + k0 + scol, (char*)sA + chunk * 1024);
      gload16(Bw + (size_t)(bn + chunk * 8 + srow) * 1024 + k0 + scol, (char*)sB + chunk * 1024);
    }
    __syncthreads();
#pragma unroll
    for (int kk = 0; kk < 2; ++kk) {
      const int cb = ((kk << 6) | (g << 4)) ^ ((s15 & 7) << 4);
      bf16x8 af[4], bf[4];
#pragma unroll
      for (int mm = 0; mm < 4; ++mm)
        af[mm] = *(const bf16x8*)((const char*)sA + (wr * 64 + mm * 16 + s15) * 128 + cb);
#pragma unroll
      for (int nn = 0; nn < 4; ++nn)
        bf[nn] = *(const bf16x8*)((const char*)sB + (wc * 64 + nn * 16 + s15) * 128 + cb);
#pragma unroll
      for (int mm = 0; mm < 4; ++mm)
#pragma unroll
        for (int nn = 0; nn < 4; ++nn)
          acc[mm][nn] = __builtin_amdgcn_mfma_f32_16x16x32_bf16(af[mm], bf[nn], acc[mm][nn], 0, 0, 0);
    }
  }

  if (MODE == 1) {
    const int region = bn >> 10;               // 0=Q 1=K 2=V (block-uniform)
    const float a = (region == 0) ? QSCALE : 1.f;
#pragma unroll
    for (int mm = 0; mm < 4; ++mm)
#pragma unroll
      for (int nn = 0; nn < 4; ++nn) {
        const int col = bn + wc * 64 + nn * 16 + s15;
        const int colr = col & 1023;
        const int row0 = bm + wr * 64 + mm * 16 + (g << 2);
        if (region == 2) {
          ushort4 w;
          w.x = f2bf(acc[mm][nn][0]); w.y = f2bf(acc[mm][nn][1]);
          w.z = f2bf(acc[mm][nn][2]); w.w = f2bf(acc[mm][nn][3]);
          *(ushort4*)(Cvt + (size_t)colr * BT_ + row0) = w;   // V^T[d][token]
        } else {
          u16* dst = region ? Ck : Cq;
#pragma unroll
          for (int r = 0; r < 4; ++r)
            dst[(size_t)(row0 + r) * 1024 + colr] = f2bf(acc[mm][nn][r] * a);
        }
      }
  } else {
#pragma unroll
    for (int mm = 0; mm < 4; ++mm)
#pragma unroll
      for (int nn = 0; nn < 4; ++nn) {
        const int col = bn + wc * 64 + nn * 16 + s15;
        const int row0 = bm + wr * 64 + mm * 16 + (g << 2);
        const float bv = bias[col];
#pragma unroll
        for (int r = 0; r < 4; ++r) {
          float v = acc[mm][nn][r] + bv;
          v = rowmask[row0 + r] ? 0.f : v;
          Cf[(size_t)(row0 + r) * 1024 + col] = v;
        }
      }
  }
}

// ---------------- Flash attention (causal), O^T = V^T @ P^T, P in registers ----------
// Grid: (B*H, 8). 512 threads = 8 waves x 16 q-rows. Each block processes the
// q-tile PAIR (j, 15-j) -> uniform 36 KV-tiles per block (load balance).
// KV tile 64 double-buffered, global_load_lds staging (1 per thread per buffer),
// defer-max (THR=8, exp2 domain), setprio around MFMA clusters.
__global__ __launch_bounds__(512, 4) void attn_fwd(
    const u16* __restrict__ Q, const u16* __restrict__ K,
    const u16* __restrict__ VT, const unsigned char* __restrict__ pm,
    const unsigned char* __restrict__ tileflag, u16* __restrict__ O)
{
  __shared__ __align__(16) u16 sK[2][64 * 64];
  __shared__ __align__(16) u16 sV[2][64 * 64];
  const int tid = threadIdx.x;
  const int lane = tid & 63, wave = tid >> 6;      // 8 waves
  const int g = lane >> 4, s15 = lane & 15;
  const int bh = blockIdx.x, b = bh >> 4, h = bh & 15;
  const int jpair = blockIdx.y;                    // 0..7
  const size_t tokbase = (size_t)b * T_;

  // staging geometry: thread covers KV row tid>>3, 16B chunk (pre-swizzled source)
  const int srow = tid >> 3;                       // 0..63
  const int sc = (tid & 7) ^ (srow & 7);
  const u16* Kb0 = K + tokbase * D_ + h * 64 + sc * 8;
  const u16* Vb0 = VT + (size_t)(h * 64) * BT_ + tokbase + sc * 8;

#pragma unroll
  for (int half = 0; half < 2; ++half) {
    const int qt = half ? (15 - jpair) : jpair;
    const int q0 = qt * 128;
    const int qw = q0 + wave * 16;
    const int nt = 2 * qt + 2;

    // Q fragments (B-operand of QK^T): lane holds Q[qw+s15][ks*32+g*8 ..+7]
    bf16x8 qf[2];
#pragma unroll
    for (int ks = 0; ks < 2; ++ks)
      qf[ks] = *(const bf16x8*)(Q + (tokbase + qw + s15) * D_ + h * 64 + ks * 32 + g * 8);

    f32x4 o[4] = {};
    float m_ = -1e30f, l_ = 0.f;

    // prologue: stage tile 0 (buf 0)
    gload16(Kb0 + (size_t)srow * D_,  (char*)(&sK[0][0]) + tid * 16);
    gload16(Vb0 + (size_t)srow * BT_, (char*)(&sV[0][0]) + tid * 16);
    __syncthreads();

    for (int t = 0; t < nt; ++t) {
      const int kv0 = t << 6;
      if (t + 1 < nt) {        // stage next tile into other buffer (overlaps compute)
        const int nb = (t + 1) & 1;
        gload16(Kb0 + (size_t)(kv0 + 64 + srow) * D_,  (char*)(&sK[nb][0]) + tid * 16);
        gload16(Vb0 + (size_t)srow * BT_ + kv0 + 64,   (char*)(&sV[nb][0]) + tid * 16);
      }

      if (kv0 <= qw + 15) {    // wave-uniform causal gating
        const u16* kb_ = &sK[t & 1][0];
        const u16* vb_ = &sV[t & 1][0];

        // S^T[j][i] = sum_d K[j,d] * Q[i,d]
        f32x4 st[4] = {};
#pragma unroll
        for (int ks = 0; ks < 2; ++ks) {
          bf16x8 kf[4];
#pragma unroll
          for (int jf = 0; jf < 4; ++jf)
            kf[jf] = *(const bf16x8*)(kb_ + (jf * 16 + s15) * 64 + (((ks * 4 + g) ^ (s15 & 7)) << 3));
          __builtin_amdgcn_s_setprio(1);
#pragma unroll
          for (int jf = 0; jf < 4; ++jf)
            st[jf] = __builtin_amdgcn_mfma_f32_16x16x32_bf16(kf[jf], qf[ks], st[jf], 0, 0, 0);
          __builtin_amdgcn_s_setprio(0);
        }

        // causal mask: j = kv0+jf*16+g*4+r, i = qw+s15
        if (kv0 + 63 > qw) {
          const int iq = qw + s15;
#pragma unroll
          for (int jf = 0; jf < 4; ++jf) {
            const int jb = kv0 + jf * 16 + g * 4;
#pragma unroll
            for (int r = 0; r < 4; ++r)
              if (jb + r > iq) st[jf][r] = -1e30f;
          }
        }
        if (tileflag[b * 32 + t]) {   // key padding (uniform; all-false fast path)
#pragma unroll
          for (int jf = 0; jf < 4; ++jf) {
            const int jb = kv0 + jf * 16 + g * 4;
            uchar4 p4 = *(const uchar4*)(pm + b * T_ + jb);
            const unsigned char* pr = (const unsigned char*)&p4;
#pragma unroll
            for (int r = 0; r < 4; ++r)
              if (pr[r]) st[jf][r] = -1e30f;
          }
        }

        // online softmax, row i = s15 (lane-local stats), defer-max THR=8
        float tm = -1e30f;
#pragma unroll
        for (int jf = 0; jf < 4; ++jf)
          tm = fmaxf(tm, fmaxf(fmaxf(st[jf][0], st[jf][1]), fmaxf(st[jf][2], st[jf][3])));
        tm = fmaxf(tm, __shfl_xor(tm, 16));
        tm = fmaxf(tm, __shfl_xor(tm, 32));
        if (!__all(tm <= m_ + 8.f)) {
          const float mn = fmaxf(m_, tm);
          const float ac = __builtin_amdgcn_exp2f(m_ - mn);
          m_ = mn;
          l_ *= ac;
#pragma unroll
          for (int df = 0; df < 4; ++df) o[df] *= ac;
        }
        float s = 0.f;
#pragma unroll
        for (int jf = 0; jf < 4; ++jf)
#pragma unroll
          for (int r = 0; r < 4; ++r) {
            const float p = __builtin_amdgcn_exp2f(st[jf][r] - m_);
            st[jf][r] = p;
            s += p;
          }
        s += __shfl_xor(s, 16);
        s += __shfl_xor(s, 32);
        l_ += s;

        // O^T += V^T @ P^T, P fragments built via cvt_pk + permlane swaps
#pragma unroll
        for (int kb2 = 0; kb2 < 2; ++kb2) {
          bf16x8 vf[4];
#pragma unroll
          for (int df = 0; df < 4; ++df)
            vf[df] = *(const bf16x8*)(vb_ + (df * 16 + s15) * 64 + (((kb2 * 4 + g) ^ (s15 & 7)) << 3));
          unsigned w00, w01, w10, w11;
          asm("v_cvt_pk_bf16_f32 %0, %1, %2" : "=v"(w00) : "v"(st[2*kb2][0]),   "v"(st[2*kb2][1]));
          asm("v_cvt_pk_bf16_f32 %0, %1, %2" : "=v"(w01) : "v"(st[2*kb2][2]),   "v"(st[2*kb2][3]));
          asm("v_cvt_pk_bf16_f32 %0, %1, %2" : "=v"(w10) : "v"(st[2*kb2+1][0]), "v"(st[2*kb2+1][1]));
          asm("v_cvt_pk_bf16_f32 %0, %1, %2" : "=v"(w11) : "v"(st[2*kb2+1][2]), "v"(st[2*kb2+1][3]));
          asm("v_permlane32_swap_b32 %0, %1" : "+v"(w00), "+v"(w10));
          asm("v_permlane16_swap_b32 %0, %1" : "+v"(w00), "+v"(w10));
          asm("v_permlane32_swap_b32 %0, %1" : "+v"(w01), "+v"(w11));
          asm("v_permlane16_swap_b32 %0, %1" : "+v"(w01), "+v"(w11));
          union { unsigned u[4]; bf16x8 v; } pf;
          pf.u[0] = w00; pf.u[1] = w01; pf.u[2] = w10; pf.u[3] = w11;
          __builtin_amdgcn_s_setprio(1);
#pragma unroll
          for (int df = 0; df < 4; ++df)
            o[df] = __builtin_amdgcn_mfma_f32_16x16x32_bf16(vf[df], pf.v, o[df], 0, 0, 0);
          __builtin_amdgcn_s_setprio(0);
        }
      }
      __syncthreads();   // publishes stage(t+1); all reads of buf[t&1] done
    }

    // finalize: O[i][d] = O^T[d][i] / l  (all lane-local)
    const float inv = 1.f / l_;
    u16* orow = O + (tokbase + qw + s15) * D_ + h * 64 + g * 4;
#pragma unroll
    for (int df = 0; df < 4; ++df) {
      ushort4 w;
      w.x = f2bf(o[df][0] * inv); w.y = f2bf(o[df][1] * inv);
      w.z = f2bf(o[df][2] * inv); w.w = f2bf(o[df][3] * inv);
      *(ushort4*)(orow + df * 16) = w;
    }
  }
}

// ---------------- launcher ----------------
extern "C" void kernel_launch(void* const* d_in, const int* in_sizes, int n_in,
                              void* d_out, int out_size, void* d_ws, size_t ws_size,
                              hipStream_t stream)
{
  const float* x  = (const float*)d_in[0];
  const unsigned char* pm = (const unsigned char*)d_in[1];
  const float* Wq = (const float*)d_in[2];
  const float* Wk = (const float*)d_in[3];
  const float* Wv = (const float*)d_in[4];
  const float* Wo = (const float*)d_in[5];
  const float* bo = (const float*)d_in[6];
  float* out = (float*)d_out;

  char* w = (char*)d_ws;
  u16* xb  = (u16*)w; w += (size_t)BT_ * D_ * 2;
  u16* wqb = (u16*)w; w += (size_t)D_ * D_ * 2;   // wq|wk|wv contiguous -> fused [3072,1024]
  u16* wkb = (u16*)w; w += (size_t)D_ * D_ * 2;
  u16* wvb = (u16*)w; w += (size_t)D_ * D_ * 2;
  u16* wob = (u16*)w; w += (size_t)D_ * D_ * 2;
  u16* qb  = (u16*)w; w += (size_t)BT_ * D_ * 2;
  u16* kbf = (u16*)w; w += (size_t)BT_ * D_ * 2;
  u16* vt  = (u16*)w; w += (size_t)BT_ * D_ * 2;  // V^T [1024][8192]
  u16* ao  = (u16*)w; w += (size_t)BT_ * D_ * 2;
  unsigned char* flags = (unsigned char*)w; w += 256;

  const int nx4 = BT_ * D_ / 4;
  const int nw4 = D_ * D_ / 4;
  cvt_bf16<<<nx4 / 256, 256, 0, stream>>>(x, xb, nx4);
  cvt_bf16<<<nw4 / 256, 256, 0, stream>>>(Wq, wqb, nw4);
  cvt_bf16<<<nw4 / 256, 256, 0, stream>>>(Wk, wkb, nw4);
  cvt_bf16<<<nw4 / 256, 256, 0, stream>>>(Wv, wvb, nw4);
  cvt_bf16<<<nw4 / 256, 256, 0, stream>>>(Wo, wob, nw4);
  pm_flags<<<1, 128, 0, stream>>>(pm, flags);

  gemm_bt<1><<<dim3(64, 24), 256, 0, stream>>>(xb, wqb, nullptr, nullptr, nullptr, qb, kbf, vt);

  attn_fwd<<<dim3(B_ * H_, 8), 512, 0, stream>>>(qb, kbf, vt, pm, flags, ao);

  gemm_bt<0><<<dim3(64, 8), 256, 0, stream>>>(ao, wob, out, bo, pm, nullptr, nullptr, nullptr);
}